// Round 15
// baseline (61.351 us; speedup 1.0000x reference)
//
#include <hip/hip_runtime.h>
#include <math.h>

// Net: 4 layers of out = 0.8*(x@W^T) + 0.2*max_i(W[o,i]*x[b,i]) + b
// B=1024, dims 256 -> 512 -> 512 -> 512 -> 1. All fp32.
//
// R15: clean test of the LDS-pipe model (ds_read_b128 ~12cyc/CU => R7's
// 4096 reads/CU/layer ~ 51us ~ the measured 57us wall; R12's same-count
// flat result fits; R11 was confounded by 2x W traffic).
// Decomposition: thread t owns 2 o's (t&255, +256) x 4 rows x HALF of K
// (half = t>>8). Per-CU h-reads halve (2048/layer); W bytes+instr, VALU
// products, occupancy all EXACTLY R7. Split-K combine per layer via 32KB
// LDS scratch (tiny). R7's proven group-of-4 n-temp W prefetch, all named
// registers (R6/R9 scratch lessons), packed fp32 + max3.

#define NT   512

typedef float v2f __attribute__((ext_vector_type(2)));

// ws layout in float4 units
#define WT1_OFF 0
#define WT2_OFF 33280    // 32768 + 512 pad
#define WT3_OFF 99328    // 33280 + 65536 + 512 pad

__global__ __launch_bounds__(256) void transpose_all(
    const float* __restrict__ W1, const float* __restrict__ W2,
    const float* __restrict__ W3, float4* __restrict__ ws)
{
    const int tid = blockIdx.x * 256 + threadIdx.x;   // 0 .. 163839
    const float* W;
    float4* WT;
    int o, k4, K;
    if (tid < 32768) {                    // W1: O=512, K=256, K4=64
        W = W1; WT = ws + WT1_OFF; K = 256;
        o = tid >> 6; k4 = tid & 63;
    } else if (tid < 98304) {             // W2: O=512, K=512, K4=128
        const int idx = tid - 32768;
        W = W2; WT = ws + WT2_OFF; K = 512;
        o = idx >> 7; k4 = idx & 127;
    } else {                              // W3: O=512, K=512, K4=128
        const int idx = tid - 98304;
        W = W3; WT = ws + WT3_OFF; K = 512;
        o = idx >> 7; k4 = idx & 127;
    }
    float4 v = *(const float4*)&W[(size_t)o * K + 4 * k4];
    WT[(size_t)k4 * 512 + o] = v;
}

// One k4 for one (o,row) pair: 2 pk_mul + 2 pk_add + 2 max3.
#define PROD(S, M, W01, W23, H01, H23)                                      \
    {                                                                       \
        v2f p = (W01) * (H01);                                              \
        S += p; M = fmaxf(fmaxf(M, p[0]), p[1]);                            \
        p = (W23) * (H23);                                                  \
        S += p; M = fmaxf(fmaxf(M, p[0]), p[1]);                            \
    }

// Split-K layer: thread t computes partial (sum,max) for o in {t&255,
// (t&255)+256}, rows 0..3, over its K-half; combine via LDS scratch.
__device__ __forceinline__ void layer_split(
    const float (*__restrict__ hin)[512],
    float (*__restrict__ hout)[512],
    const float4* __restrict__ WT,    // [K4][512] coalesced panels
    const float* __restrict__ bias,
    float4* __restrict__ scr,         // [2048]: s at [o*2+half], m at +1024
    int K4, int t)
{
    const int o0   = t & 255;
    const int half = t >> 8;
    const int o1   = o0 + 256;
    const int K4h  = K4 >> 1;

    v2f s0[4], s1[4];
    float m0[4], m1[4];
    #pragma unroll
    for (int r = 0; r < 4; ++r) {
        s0[r] = (v2f)0.f; s1[r] = (v2f)0.f;
        m0[r] = -INFINITY; m1[r] = -INFINITY;
    }

    const float4* wp0 = WT + (size_t)(half * K4h) * 512 + o0;
    const float4* wp1 = wp0 + 256;
    const float4* h0p = (const float4*)hin[0] + half * K4h;
    const float4* h1p = (const float4*)hin[1] + half * K4h;
    const float4* h2p = (const float4*)hin[2] + half * K4h;
    const float4* h3p = (const float4*)hin[3] + half * K4h;

    // group-of-4 prefetch, both panels (R7 n-temp pattern, all named)
    float4 u0 = wp0[0], u1 = wp0[512], u2 = wp0[1024], u3 = wp0[1536];
    float4 v0 = wp1[0], v1 = wp1[512], v2 = wp1[1024], v3 = wp1[1536];

    for (int kg = 0; kg < K4h; kg += 4) {
        float4 nu0 = u0, nu1 = u1, nu2 = u2, nu3 = u3;
        float4 nv0 = v0, nv1 = v1, nv2 = v2, nv3 = v3;
        if (kg + 4 < K4h) {               // uniform (scalar) branch
            const float4* q0 = wp0 + (size_t)(kg + 4) * 512;
            const float4* q1 = wp1 + (size_t)(kg + 4) * 512;
            nu0 = q0[0]; nu1 = q0[512]; nu2 = q0[1024]; nu3 = q0[1536];
            nv0 = q1[0]; nv1 = q1[512]; nv2 = q1[1024]; nv3 = q1[1536];
        }
        #pragma unroll
        for (int j = 0; j < 4; ++j) {
            const float4 wu = (j == 0) ? u0 : (j == 1) ? u1 : (j == 2) ? u2 : u3;
            const float4 wv = (j == 0) ? v0 : (j == 1) ? v1 : (j == 2) ? v2 : v3;
            const int q = kg + j;
            v2f u01; u01[0] = wu.x; u01[1] = wu.y;
            v2f u23; u23[0] = wu.z; u23[1] = wu.w;
            v2f w01; w01[0] = wv.x; w01[1] = wv.y;
            v2f w23; w23[0] = wv.z; w23[1] = wv.w;
            #pragma unroll
            for (int r = 0; r < 4; ++r) {
                const float4 h = (r == 0) ? h0p[q] : (r == 1) ? h1p[q]
                               : (r == 2) ? h2p[q] : h3p[q];   // uniform bcast
                v2f h01; h01[0] = h.x; h01[1] = h.y;
                v2f h23; h23[0] = h.z; h23[1] = h.w;
                PROD(s0[r], m0[r], u01, u23, h01, h23);
                PROD(s1[r], m1[r], w01, w23, h01, h23);
            }
        }
        u0 = nu0; u1 = nu1; u2 = nu2; u3 = nu3;
        v0 = nv0; v1 = nv1; v2 = nv2; v3 = nv3;
    }

    // ---- write partials: pack (rows) into float4 ----
    float4 ps0, pm0, ps1, pm1;
    ps0.x = s0[0][0] + s0[0][1]; ps0.y = s0[1][0] + s0[1][1];
    ps0.z = s0[2][0] + s0[2][1]; ps0.w = s0[3][0] + s0[3][1];
    ps1.x = s1[0][0] + s1[0][1]; ps1.y = s1[1][0] + s1[1][1];
    ps1.z = s1[2][0] + s1[2][1]; ps1.w = s1[3][0] + s1[3][1];
    pm0.x = m0[0]; pm0.y = m0[1]; pm0.z = m0[2]; pm0.w = m0[3];
    pm1.x = m1[0]; pm1.y = m1[1]; pm1.z = m1[2]; pm1.w = m1[3];

    scr[o0 * 2 + half]        = ps0;
    scr[o1 * 2 + half]        = ps1;
    scr[1024 + o0 * 2 + half] = pm0;
    scr[1024 + o1 * 2 + half] = pm1;
    __syncthreads();

    // ---- merge: thread t finalizes o = t ----
    const float4 sa = scr[t * 2 + 0];
    const float4 sb = scr[t * 2 + 1];
    const float4 ma = scr[1024 + t * 2 + 0];
    const float4 mb = scr[1024 + t * 2 + 1];
    const float bo = bias[t];
    hout[0][t] = fmaf(0.2f, fmaxf(ma.x, mb.x), fmaf(0.8f, sa.x + sb.x, bo));
    hout[1][t] = fmaf(0.2f, fmaxf(ma.y, mb.y), fmaf(0.8f, sa.y + sb.y, bo));
    hout[2][t] = fmaf(0.2f, fmaxf(ma.z, mb.z), fmaf(0.8f, sa.z + sb.z, bo));
    hout[3][t] = fmaf(0.2f, fmaxf(ma.w, mb.w), fmaf(0.8f, sa.w + sb.w, bo));
    // caller barrier publishes hout and releases scr
}

__global__ __launch_bounds__(NT) void net_fused(
    const float* __restrict__ x,
    const float4* __restrict__ WT1, const float* __restrict__ b1,
    const float4* __restrict__ WT2, const float* __restrict__ b2,
    const float4* __restrict__ WT3, const float* __restrict__ b3,
    const float* __restrict__ W4,   const float* __restrict__ b4,
    float* __restrict__ out)
{
    __shared__ __align__(16) float ha[4][512];
    __shared__ __align__(16) float hb[4][512];
    __shared__ __align__(16) float4 scr[2048];   // 32 KB split-K scratch
    __shared__ float red_s[8][4];
    __shared__ float red_m[8][4];

    const int t = threadIdx.x;
    const int row0 = blockIdx.x * 4;

    // stage x rows (4 x 256) into ha: one float2 per thread
    {
        const int r = t >> 7;
        const int c = (t & 127) * 2;
        float2 v = *(const float2*)&x[(size_t)(row0 + r) * 256 + c];
        ha[r][c]     = v.x;
        ha[r][c + 1] = v.y;
    }
    __syncthreads();

    layer_split(ha, hb, WT1, b1, scr, 64,  t);   // x  -> h1
    __syncthreads();
    layer_split(hb, ha, WT2, b2, scr, 128, t);   // h1 -> h2
    __syncthreads();
    layer_split(ha, hb, WT3, b3, scr, 128, t);   // h2 -> h3
    __syncthreads();

    // ---- layer 4: O=1 ----
    const float w4 = W4[t];
    float ps0, ps1, ps2, ps3, pm0, pm1, pm2, pm3;
    {
        float p0 = w4 * hb[0][t]; ps0 = p0; pm0 = p0;
        float p1 = w4 * hb[1][t]; ps1 = p1; pm1 = p1;
        float p2 = w4 * hb[2][t]; ps2 = p2; pm2 = p2;
        float p3 = w4 * hb[3][t]; ps3 = p3; pm3 = p3;
    }
    #pragma unroll
    for (int off = 32; off; off >>= 1) {
        ps0 += __shfl_xor(ps0, off, 64);
        pm0 = fmaxf(pm0, __shfl_xor(pm0, off, 64));
        ps1 += __shfl_xor(ps1, off, 64);
        pm1 = fmaxf(pm1, __shfl_xor(pm1, off, 64));
        ps2 += __shfl_xor(ps2, off, 64);
        pm2 = fmaxf(pm2, __shfl_xor(pm2, off, 64));
        ps3 += __shfl_xor(ps3, off, 64);
        pm3 = fmaxf(pm3, __shfl_xor(pm3, off, 64));
    }
    const int lane = t & 63;
    const int wave = t >> 6;
    if (lane == 0) {
        red_s[wave][0] = ps0; red_m[wave][0] = pm0;
        red_s[wave][1] = ps1; red_m[wave][1] = pm1;
        red_s[wave][2] = ps2; red_m[wave][2] = pm2;
        red_s[wave][3] = ps3; red_m[wave][3] = pm3;
    }
    __syncthreads();

    if (t < 4) {
        float s = red_s[0][t];
        float m = red_m[0][t];
        #pragma unroll
        for (int w = 1; w < 8; ++w) {
            s += red_s[w][t];
            m = fmaxf(m, red_m[w][t]);
        }
        out[row0 + t] = fmaf(0.2f, m, fmaf(0.8f, s, b4[0]));
    }
}

extern "C" void kernel_launch(void* const* d_in, const int* in_sizes, int n_in,
                              void* d_out, int out_size, void* d_ws, size_t ws_size,
                              hipStream_t stream)
{
    const float* x  = (const float*)d_in[0];
    const float* W1 = (const float*)d_in[1];
    const float* b1 = (const float*)d_in[2];
    const float* W2 = (const float*)d_in[3];
    const float* b2 = (const float*)d_in[4];
    const float* W3 = (const float*)d_in[5];
    const float* b3 = (const float*)d_in[6];
    const float* W4 = (const float*)d_in[7];
    const float* b4 = (const float*)d_in[8];

    float4* ws4 = (float4*)d_ws;

    transpose_all<<<640, 256, 0, stream>>>(W1, W2, W3, ws4);

    net_fused<<<256, NT, 0, stream>>>(
        x,
        ws4 + WT1_OFF, b1,
        ws4 + WT2_OFF, b2,
        ws4 + WT3_OFF, b3,
        W4, b4,
        (float*)d_out);
}